// Round 14
// baseline (804.961 us; speedup 1.0000x reference)
//
#include <hip/hip_runtime.h>
#include <hip/hip_bf16.h>

typedef __attribute__((ext_vector_type(8))) short bf16x8;
typedef __attribute__((ext_vector_type(4))) short short4v;
typedef __attribute__((ext_vector_type(4))) float f32x4;

#define MFMA16(A, B, C) __builtin_amdgcn_mfma_f32_16x16x32_bf16((A), (B), (C), 0, 0, 0)
#define GLDS16(g, l)                                                            \
  __builtin_amdgcn_global_load_lds(                                             \
      (const __attribute__((address_space(1))) void*)(g),                       \
      (__attribute__((address_space(3))) void*)(l), 16, 0, 0)

__device__ __forceinline__ short f2bf(float f) {
  union { float f; unsigned u; } v; v.f = f;
  return (short)((v.u + 0x7fffu + ((v.u >> 16) & 1u)) >> 16);
}

__device__ __forceinline__ void blk_barrier() {
  asm volatile("" ::: "memory");
  __builtin_amdgcn_s_barrier();
  asm volatile("" ::: "memory");
}

// ------- fp32 -> bf16 convert, 3 arrays in one launch (grid-stride) ------------
__global__ __launch_bounds__(256) void cvt3_kernel(const float* __restrict__ in0,
                                                   short* __restrict__ out0, int n0,
                                                   const float* __restrict__ in1,
                                                   short* __restrict__ out1, int n1,
                                                   const float* __restrict__ in2,
                                                   short* __restrict__ out2, int n2) {
  int i = blockIdx.x * 256 + threadIdx.x;
  const int stride = gridDim.x * 256;
  const int total = n0 + n1 + n2;
  for (; i < total; i += stride) {
    const float* src;
    short* dst;
    int j = i;
    if (j < n0) { src = in0; dst = out0; }
    else if ((j -= n0) < n1) { src = in1; dst = out1; }
    else { j -= n1; src = in2; dst = out2; }
    f32x4 v = ((const f32x4*)src)[j];
    short4v o;
    o[0] = f2bf(v[0]); o[1] = f2bf(v[1]); o[2] = f2bf(v[2]); o[3] = f2bf(v[3]);
    ((short4v*)dst)[j] = o;
  }
}

// ------------ bf16 GEMM, 256x256 8-phase (r5-proven, 452us on qkv) -------------
// mode 0 (qkv): V-columns (col%384>=256) stored TRANSPOSED into mixed's dead
// V-region: VT(b,h,d,t) @ row (b*1024 + d*8 + (t>>7)), col (h*384+256+(t&127)).
__global__ __launch_bounds__(512, 2) void gemm_bt8(const short* __restrict__ A,
                                                   const short* __restrict__ B,
                                                   const float* __restrict__ bias,
                                                   const float* __restrict__ resid,
                                                   short* __restrict__ Cb,
                                                   float* __restrict__ Cf,
                                                   int Mtiles, int Nn, int K, int mode) {
  __shared__ short sA[2][2][8192];  // [buf][half][128*64]
  __shared__ short sB[2][2][8192];
  const int tid = threadIdx.x;
  const int w = tid >> 6, l = tid & 63;
  const int wm = w >> 2, wn = w & 3;
  const int fr = l & 15, g4 = l >> 4, sx = l & 7;

  // T1: bijective XCD swizzle (m204)
  const int nwg = gridDim.x;
  const int qq = nwg >> 3, rr = nwg & 7;
  const int xcd = blockIdx.x & 7, sub = blockIdx.x >> 3;
  const int swz = (xcd < rr ? xcd * (qq + 1) : rr * (qq + 1) + (xcd - rr) * qq) + sub;
  const int rowBase = (swz % Mtiles) * 256;
  const int colBase = (swz / Mtiles) * 256;

  const int NT = K >> 6;
  const int swcol = ((l & 7) ^ (l >> 3)) * 8;  // inverse-swizzled source slot
  const short* Ag = A + (size_t)(rowBase + w * 8 + (l >> 3)) * K + swcol;
  const short* Bg = B + (size_t)(colBase + w * 8 + (l >> 3)) * K + swcol;
  const size_t q1 = (size_t)64 * K;
  const size_t hh = (size_t)128 * K;

#define STAGE_A(buf, h, ko)                                     \
  GLDS16(Ag + (h) * hh + (ko), &sA[buf][h][w * 512]);           \
  GLDS16(Ag + (h) * hh + q1 + (ko), &sA[buf][h][(8 + w) * 512]);
#define STAGE_B(buf, h, ko)                                     \
  GLDS16(Bg + (h) * hh + (ko), &sB[buf][h][w * 512]);           \
  GLDS16(Bg + (h) * hh + q1 + (ko), &sB[buf][h][(8 + w) * 512]);
#define RD_A(buf, m, ks) \
  (*(const bf16x8*)&sA[buf][wm][(((m) * 16 + fr) << 6) + ((((ks) * 4 + g4) ^ sx) << 3)])
#define RD_B(buf, nf, ks) \
  (*(const bf16x8*)&sB[buf][wn >> 1][((((wn & 1) * 64) + (nf) * 16 + fr) << 6) + ((((ks) * 4 + g4) ^ sx) << 3)])

  f32x4 acc[8][4];
#pragma unroll
  for (int m = 0; m < 8; m++)
#pragma unroll
    for (int n = 0; n < 4; n++) acc[m][n] = (f32x4)(0.0f);

  // prologue: stage tile 0 into buf 0
  STAGE_A(0, 0, 0); STAGE_A(0, 1, 0);
  STAGE_B(0, 0, 0); STAGE_B(0, 1, 0);

  for (int t = 0; t < NT; ++t) {
    const int cur = t & 1, nxt = cur ^ 1;
    const size_t ko = (size_t)(t + 1) << 6;
    bf16x8 bfr[4][2], af[2][2];
    // ---- phase 0: stage A halves of t+1, counted vmcnt, B-frags + A m0,m1 ----
    if (t + 1 < NT) {
      STAGE_A(nxt, 0, ko); STAGE_A(nxt, 1, ko);
      asm volatile("s_waitcnt vmcnt(4)" ::: "memory");  // tile t's 8 loads done
    } else {
      asm volatile("s_waitcnt vmcnt(0)" ::: "memory");  // epilogue drain
    }
    blk_barrier();
#pragma unroll
    for (int nf = 0; nf < 4; nf++) {
      bfr[nf][0] = RD_B(cur, nf, 0);
      bfr[nf][1] = RD_B(cur, nf, 1);
    }
    af[0][0] = RD_A(cur, 0, 0); af[0][1] = RD_A(cur, 0, 1);
    af[1][0] = RD_A(cur, 1, 0); af[1][1] = RD_A(cur, 1, 1);
    __builtin_amdgcn_s_setprio(1);
#pragma unroll
    for (int mi = 0; mi < 2; mi++)
#pragma unroll
      for (int nf = 0; nf < 4; nf++) {
        acc[mi][nf] = MFMA16(af[mi][0], bfr[nf][0], acc[mi][nf]);
        acc[mi][nf] = MFMA16(af[mi][1], bfr[nf][1], acc[mi][nf]);
      }
    __builtin_amdgcn_s_setprio(0);
    blk_barrier();
    // ---- phases 1..3: A m{2p,2p+1}; ph1 stages both B halves of t+1 ----
#pragma unroll
    for (int p = 1; p < 4; p++) {
      af[0][0] = RD_A(cur, 2 * p, 0);     af[0][1] = RD_A(cur, 2 * p, 1);
      af[1][0] = RD_A(cur, 2 * p + 1, 0); af[1][1] = RD_A(cur, 2 * p + 1, 1);
      if (p == 1 && t + 1 < NT) {
        STAGE_B(nxt, 0, ko); STAGE_B(nxt, 1, ko);
      }
      blk_barrier();
      __builtin_amdgcn_s_setprio(1);
#pragma unroll
      for (int mi = 0; mi < 2; mi++)
#pragma unroll
        for (int nf = 0; nf < 4; nf++) {
          acc[2 * p + mi][nf] = MFMA16(af[mi][0], bfr[nf][0], acc[2 * p + mi][nf]);
          acc[2 * p + mi][nf] = MFMA16(af[mi][1], bfr[nf][1], acc[2 * p + mi][nf]);
        }
      __builtin_amdgcn_s_setprio(0);
      blk_barrier();
    }
  }

  // epilogue: C row=(l>>4)*4+j, col=fr within each 16x16 frag (m89/m91)
#pragma unroll
  for (int m = 0; m < 8; m++) {
    const int row0 = rowBase + wm * 128 + m * 16 + g4 * 4;
#pragma unroll
    for (int n = 0; n < 4; n++) {
      const int col = colBase + wn * 64 + n * 16 + fr;
      const float bc = bias[col];
      if (mode == 0) {
        const int cmod = col % 384;
        if (cmod >= 256) {
          // V column: transposed-packed store into mixed's dead V-region.
          const int h = col / 384, d = cmod - 256;
          const int b = row0 >> 10, t0 = row0 & 1023;
          short4v pv;
#pragma unroll
          for (int j = 0; j < 4; j++) pv[j] = f2bf(acc[m][n][j] + bc);
          *(short4v*)&Cb[(size_t)(b * 1024 + d * 8 + (t0 >> 7)) * Nn +
                         h * 384 + 256 + (t0 & 127)] = pv;
        } else {
#pragma unroll
          for (int j = 0; j < 4; j++)
            Cb[(size_t)(row0 + j) * Nn + col] = f2bf(acc[m][n][j] + bc);
        }
      } else {
#pragma unroll
        for (int j = 0; j < 4; j++) {
          const size_t idx = (size_t)(row0 + j) * Nn + col;
          Cf[idx] = acc[m][n][j] + bc + resid[idx];
        }
      }
    }
  }
#undef STAGE_A
#undef STAGE_B
#undef RD_A
#undef RD_B
}

// ---- bf16 GEMM, 128x256 tile, BK=32, 2 blocks/CU (r6; wins on small grids) ----
__global__ __launch_bounds__(512, 4) void gemm_bt(const short* __restrict__ A,
                                                  const short* __restrict__ B,
                                                  const float* __restrict__ bias,
                                                  const float* __restrict__ resid,
                                                  short* __restrict__ Cb,
                                                  float* __restrict__ Cf,
                                                  int Mtiles, int Nn, int K, int mode) {
  __shared__ short sA[2][128 * 32];  // 8 KiB per buf
  __shared__ short sB[2][256 * 32];  // 16 KiB per buf
  const int tid = threadIdx.x;
  const int w = tid >> 6, l = tid & 63;
  const int wm = w >> 2, wn = w & 3;
  const int fr = l & 15, g4 = l >> 4;
  const int slotx = (g4 ^ ((fr >> 1) & 3)) << 3;

  const int nwg = gridDim.x;
  const int qq = nwg >> 3, rr = nwg & 7;
  const int xcd = blockIdx.x & 7, sub = blockIdx.x >> 3;
  const int swz = (xcd < rr ? xcd * (qq + 1) : rr * (qq + 1) + (xcd - rr) * qq) + sub;
  const int rowBase = (swz % Mtiles) * 128;
  const int colBase = (swz / Mtiles) * 256;

  const int NT = K >> 5;
  const int scol = ((l & 3) ^ ((l >> 3) & 3)) << 3;
  const short* Ag = A + (size_t)(rowBase + w * 16 + (l >> 2)) * K + scol;
  const short* Bg0 = B + (size_t)(colBase + w * 16 + (l >> 2)) * K + scol;
  const short* Bg1 = Bg0 + (size_t)128 * K;

  f32x4 acc[4][4];
#pragma unroll
  for (int m = 0; m < 4; m++)
#pragma unroll
    for (int n = 0; n < 4; n++) acc[m][n] = (f32x4)(0.0f);

  GLDS16(Ag, &sA[0][w * 512]);
  GLDS16(Bg0, &sB[0][w * 512]);
  GLDS16(Bg1, &sB[0][(8 + w) * 512]);

  for (int t = 0; t < NT; ++t) {
    const int cur = t & 1, nxt = cur ^ 1;
    const int ko = (t + 1) << 5;
    if (t + 1 < NT) {
      GLDS16(Ag + ko, &sA[nxt][w * 512]);
      GLDS16(Bg0 + ko, &sB[nxt][w * 512]);
      GLDS16(Bg1 + ko, &sB[nxt][(8 + w) * 512]);
      asm volatile("s_waitcnt vmcnt(3)" ::: "memory");
    } else {
      asm volatile("s_waitcnt vmcnt(0)" ::: "memory");
    }
    blk_barrier();

    bf16x8 af[4], bfr[4];
#pragma unroll
    for (int m = 0; m < 4; m++)
      af[m] = *(const bf16x8*)&sA[cur][(wm * 64 + m * 16 + fr) * 32 + slotx];
#pragma unroll
    for (int nf = 0; nf < 4; nf++)
      bfr[nf] = *(const bf16x8*)&sB[cur][(wn * 64 + nf * 16 + fr) * 32 + slotx];
    __builtin_amdgcn_s_setprio(1);
#pragma unroll
    for (int m = 0; m < 4; m++)
#pragma unroll
      for (int nf = 0; nf < 4; nf++)
        acc[m][nf] = MFMA16(af[m], bfr[nf], acc[m][nf]);
    __builtin_amdgcn_s_setprio(0);
    blk_barrier();
  }

#pragma unroll
  for (int m = 0; m < 4; m++) {
    const int row0 = rowBase + wm * 64 + m * 16 + g4 * 4;
#pragma unroll
    for (int n = 0; n < 4; n++) {
      const int col = colBase + wn * 64 + n * 16 + fr;
      const float bc = bias[col];
#pragma unroll
      for (int j = 0; j < 4; j++) {
        const size_t idx = (size_t)(row0 + j) * Nn + col;
        const float v = acc[m][n][j] + bc;
        if (mode == 0) Cb[idx] = f2bf(v);
        else Cf[idx] = v + resid[idx];
      }
    }
  }
}

// ------- flash attention v4: 8 waves/block (128 q-rows per staged K/V tile) ----
// Same ordering semantics as the proven v2 (per-wave exclusive p_lds slice, all
// P-scratch reuse fenced by blk_barrier); parameters only: WAVES 4->8, stagings
// per bh 136->72. Per-wave stage issues/tile = 4 -> counted wait is vmcnt(4).
// V read from mixed's dead V-region in VT layout (written by gemm_bt8 mode 0).
__global__ __launch_bounds__(512, 2) void attn_kernel(const short* __restrict__ mixed,
                                                      short* __restrict__ ctx) {
  __shared__ short sK[2][64 * 128];
  __shared__ short sV[2][128 * 64];
  __shared__ unsigned p_lds[8][16 * 36];
  const int tid = threadIdx.x;
  const int w = tid >> 6, l = tid & 63;  // w in 0..7
  const int g = l >> 4, f = l & 15, f7 = l & 7;

  const int bidx = blockIdx.x;  // 1024 = 8 xcd * 16 bh * 8 qt
  const int xcd = bidx & 7, idx = bidx >> 3;
  const int bh = (xcd << 4) | (idx >> 3);
  const int qt = idx & 7;              // 128-row q-tile
  const int b = bh >> 5, h = bh & 31;
  const int qw = qt * 128 + w * 16;    // wave owns rows [qw, qw+16)
  const float scale = 0.08838834764831845f;
  const float slope = exp2f(-0.25f * (float)(h + 1));

  const short* qptr = mixed + (size_t)b * 1024 * 12288 + h * 384;
  const short* kptr = qptr + 128;
  const short* vbase = qptr + 256;  // VT region base for (b,h)

  bf16x8 qf[4];
  {
    const short* qrow = qptr + (size_t)(qw + f) * 12288 + (g << 3);
#pragma unroll
    for (int ks = 0; ks < 4; ks++) qf[ks] = *(const bf16x8*)(qrow + ks * 32);
  }

  // 16 chunks split over 8 waves: c = c4*8 + w, c4 in 0..1 (2 issues/wave)
#define STAGE_K(buf, kt)                                                        \
  {                                                                             \
    _Pragma("unroll") for (int c4 = 0; c4 < 2; c4++) {                          \
      const int c = c4 * 8 + w;                                                 \
      const int r = c * 4 + (l >> 4);                                           \
      GLDS16(kptr + (size_t)((kt) + r) * 12288 + (((l & 15) ^ (r & 7)) << 3),   \
             &sK[buf][c << 9]);                                                 \
    }                                                                           \
  }
#define STAGE_V(buf, kt)                                                        \
  {                                                                             \
    _Pragma("unroll") for (int c4 = 0; c4 < 2; c4++) {                          \
      const int c = c4 * 8 + w;                                                 \
      const int r = c * 8 + (l >> 3);                                           \
      const int ts = ((l & 7) ^ (r & 7)) << 3;                                  \
      GLDS16(vbase + (size_t)(r * 8 + ((kt) >> 7)) * 12288 + (((kt) & 127) + ts), \
             &sV[buf][c << 9]);                                                 \
    }                                                                           \
  }

  f32x4 acc[8];
#pragma unroll
  for (int n = 0; n < 8; n++) acc[n] = (f32x4)(0.0f);
  float mrun = -1e30f, lrun = 0.0f;
  const int q = qw + f;
  unsigned* pw = p_lds[w];

  const int TT = 2 * qt + 2;
  STAGE_K(0, 0);
  STAGE_V(0, 0);

  for (int t = 0; t < TT; ++t) {
    const int cur = t & 1, nxt = cur ^ 1;
    const int kt = t << 6;
    if (t + 1 < TT) {
      STAGE_K(nxt, kt + 64);
      STAGE_V(nxt, kt + 64);
      asm volatile("s_waitcnt vmcnt(4)" ::: "memory");  // tile t's 4 issues done
    } else {
      asm volatile("s_waitcnt vmcnt(0)" ::: "memory");
    }
    blk_barrier();

    f32x4 s[4];
#pragma unroll
    for (int ksub = 0; ksub < 4; ksub++) {
      s[ksub] = (f32x4)(0.0f);
      const int r = ksub * 16 + f;
#pragma unroll
      for (int ks = 0; ks < 4; ks++) {
        bf16x8 kf = *(const bf16x8*)&sK[cur][(r << 7) + ((((ks << 2) + g) ^ f7) << 3)];
        s[ksub] = MFMA16(kf, qf[ks], s[ksub]);
      }
    }

    float ev[4][4];
    float tmax = -1e30f;
#pragma unroll
    for (int ksub = 0; ksub < 4; ksub++)
#pragma unroll
      for (int j = 0; j < 4; j++) {
        const int k = kt + ksub * 16 + g * 4 + j;
        float v = s[ksub][j] * scale + slope * (float)k;
        if (k > q) v = -1e30f;
        ev[ksub][j] = v;
        tmax = fmaxf(tmax, v);
      }
    tmax = fmaxf(tmax, __shfl_xor(tmax, 16));
    tmax = fmaxf(tmax, __shfl_xor(tmax, 32));
    const float mnew = fmaxf(mrun, tmax);  // fully-masked tail: mnew=mrun, asc=1, e=0
    const float asc = __expf(mrun - mnew);
    float psum = 0.0f;
    unsigned* pr = pw + f * 36;
#pragma unroll
    for (int ksub = 0; ksub < 4; ksub++) {
      float e0 = __expf(ev[ksub][0] - mnew);
      float e1 = __expf(ev[ksub][1] - mnew);
      float e2 = __expf(ev[ksub][2] - mnew);
      float e3 = __expf(ev[ksub][3] - mnew);
      psum += (e0 + e1) + (e2 + e3);
      unsigned w0 = (unsigned)(unsigned short)f2bf(e0) |
                    ((unsigned)(unsigned short)f2bf(e1) << 16);
      unsigned w1 = (unsigned)(unsigned short)f2bf(e2) |
                    ((unsigned)(unsigned short)f2bf(e3) << 16);
      pr[ksub * 8 + g * 2] = w0;
      pr[ksub * 8 + g * 2 + 1] = w1;
    }
    psum += __shfl_xor(psum, 16);
    psum += __shfl_xor(psum, 32);
    lrun = lrun * asc + psum;
    mrun = mnew;

    float ascB[4];
#pragma unroll
    for (int j = 0; j < 4; j++) ascB[j] = __shfl(asc, 20 * g + j);
#pragma unroll
    for (int n = 0; n < 8; n++)
#pragma unroll
      for (int j = 0; j < 4; j++) acc[n][j] *= ascB[j];

    bf16x8 pa0 = *(const bf16x8*)(pw + f * 36 + (g << 2));
    bf16x8 pa1 = *(const bf16x8*)(pw + f * 36 + 16 + (g << 2));
#pragma unroll
    for (int n = 0; n < 8; n++) {
      const int dr = (n << 4) + f;
      bf16x8 vf0 = *(const bf16x8*)&sV[cur][(dr << 6) + ((g ^ f7) << 3)];
      acc[n] = MFMA16(pa0, vf0, acc[n]);
      bf16x8 vf1 = *(const bf16x8*)&sV[cur][(dr << 6) + (((4 + g) ^ f7) << 3)];
      acc[n] = MFMA16(pa1, vf1, acc[n]);
    }
    blk_barrier();
  }

  const float linv = 1.0f / lrun;
  float invB[4];
#pragma unroll
  for (int j = 0; j < 4; j++) invB[j] = __shfl(linv, 20 * g + j);
  const int trow = b * 1024 + qw + (g << 2);
#pragma unroll
  for (int n = 0; n < 8; n++) {
    const int col = h * 128 + (n << 4) + f;
#pragma unroll
    for (int j = 0; j < 4; j++)
      ctx[(size_t)(trow + j) * 4096 + col] = f2bf(acc[n][j] * invB[j]);
  }
#undef STAGE_K
#undef STAGE_V
}

extern "C" void kernel_launch(void* const* d_in, const int* in_sizes, int n_in,
                              void* d_out, int out_size, void* d_ws, size_t ws_size,
                              hipStream_t stream) {
  const float* hs = (const float*)d_in[0];
  const float* resid = (const float*)d_in[1];
  const float* qkv_w = (const float*)d_in[2];
  const float* qkv_b = (const float*)d_in[3];
  const float* dense_w = (const float*)d_in[4];
  const float* dense_b = (const float*)d_in[5];
  float* out = (float*)d_out;

  short* hs_b = (short*)d_ws;
  short* wqkv_b = hs_b + (size_t)16777216;
  short* wd_b = wqkv_b + (size_t)50331648;
  short* mixed = wd_b + (size_t)16777216;
  short* ctx = hs_b;    // alias: hs_b dead after gemm1

  // all three fp32->bf16 converts in one launch
  cvt3_kernel<<<2048, 256, 0, stream>>>(hs, hs_b, 16777216 / 4,
                                        qkv_w, wqkv_b, 50331648 / 4,
                                        dense_w, wd_b, 16777216 / 4);
  // qkv: 256^2 structure; V-columns stored transposed in mixed (vtrans fused)
  gemm_bt8<<<dim3(48 * 16), 512, 0, stream>>>(hs_b, wqkv_b, qkv_b, nullptr,
                                              mixed, nullptr, 16, 12288, 4096, 0);
  // attn v4: 8 waves/block, 128 q-rows per staged K/V tile
  attn_kernel<<<1024, 512, 0, stream>>>(mixed, ctx);
  // dense: small grid -> 128x256 2-blocks/CU TLP structure (r6)
  gemm_bt<<<dim3(32 * 16), 512, 0, stream>>>(ctx, wd_b, dense_b, resid,
                                             nullptr, out, 32, 4096, 4096, 1);
}

// Round 15
// 783.255 us; speedup vs baseline: 1.0277x; 1.0277x over previous
//
#include <hip/hip_runtime.h>
#include <hip/hip_bf16.h>

typedef __attribute__((ext_vector_type(8))) short bf16x8;
typedef __attribute__((ext_vector_type(4))) short short4v;
typedef __attribute__((ext_vector_type(4))) float f32x4;

#define MFMA16(A, B, C) __builtin_amdgcn_mfma_f32_16x16x32_bf16((A), (B), (C), 0, 0, 0)
#define GLDS16(g, l)                                                            \
  __builtin_amdgcn_global_load_lds(                                             \
      (const __attribute__((address_space(1))) void*)(g),                       \
      (__attribute__((address_space(3))) void*)(l), 16, 0, 0)

__device__ __forceinline__ short f2bf(float f) {
  union { float f; unsigned u; } v; v.f = f;
  return (short)((v.u + 0x7fffu + ((v.u >> 16) & 1u)) >> 16);
}

__device__ __forceinline__ void blk_barrier() {
  asm volatile("" ::: "memory");
  __builtin_amdgcn_s_barrier();
  asm volatile("" ::: "memory");
}

// ------- fp32 -> bf16 convert, 3 arrays in one launch (grid-stride) ------------
__global__ __launch_bounds__(256) void cvt3_kernel(const float* __restrict__ in0,
                                                   short* __restrict__ out0, int n0,
                                                   const float* __restrict__ in1,
                                                   short* __restrict__ out1, int n1,
                                                   const float* __restrict__ in2,
                                                   short* __restrict__ out2, int n2) {
  int i = blockIdx.x * 256 + threadIdx.x;
  const int stride = gridDim.x * 256;
  const int total = n0 + n1 + n2;
  for (; i < total; i += stride) {
    const float* src;
    short* dst;
    int j = i;
    if (j < n0) { src = in0; dst = out0; }
    else if ((j -= n0) < n1) { src = in1; dst = out1; }
    else { j -= n1; src = in2; dst = out2; }
    f32x4 v = ((const f32x4*)src)[j];
    short4v o;
    o[0] = f2bf(v[0]); o[1] = f2bf(v[1]); o[2] = f2bf(v[2]); o[3] = f2bf(v[3]);
    ((short4v*)dst)[j] = o;
  }
}

// ------------ bf16 GEMM, 256x256 8-phase (r5-proven, 452us on qkv) -------------
// Stages bunched: ph0 A-halves of t+1 (vmcnt(4)), ph1 B-halves. 2 bar/phase.
// mode 0 (qkv): V-columns (col%384>=256) stored TRANSPOSED into mixed's dead
// V-region: VT(b,h,d,t) @ row (b*1024 + d*8 + (t>>7)), col (h*384+256+(t&127)).
__global__ __launch_bounds__(512, 2) void gemm_bt8(const short* __restrict__ A,
                                                   const short* __restrict__ B,
                                                   const float* __restrict__ bias,
                                                   const float* __restrict__ resid,
                                                   short* __restrict__ Cb,
                                                   float* __restrict__ Cf,
                                                   int Mtiles, int Nn, int K, int mode) {
  __shared__ short sA[2][2][8192];  // [buf][half][128*64]
  __shared__ short sB[2][2][8192];
  const int tid = threadIdx.x;
  const int w = tid >> 6, l = tid & 63;
  const int wm = w >> 2, wn = w & 3;
  const int fr = l & 15, g4 = l >> 4, sx = l & 7;

  // T1: bijective XCD swizzle (m204)
  const int nwg = gridDim.x;
  const int qq = nwg >> 3, rr = nwg & 7;
  const int xcd = blockIdx.x & 7, sub = blockIdx.x >> 3;
  const int swz = (xcd < rr ? xcd * (qq + 1) : rr * (qq + 1) + (xcd - rr) * qq) + sub;
  const int rowBase = (swz % Mtiles) * 256;
  const int colBase = (swz / Mtiles) * 256;

  const int NT = K >> 6;
  const int swcol = ((l & 7) ^ (l >> 3)) * 8;  // inverse-swizzled source slot
  const short* Ag = A + (size_t)(rowBase + w * 8 + (l >> 3)) * K + swcol;
  const short* Bg = B + (size_t)(colBase + w * 8 + (l >> 3)) * K + swcol;
  const size_t q1 = (size_t)64 * K;
  const size_t hh = (size_t)128 * K;

#define STAGE_A(buf, h, ko)                                     \
  GLDS16(Ag + (h) * hh + (ko), &sA[buf][h][w * 512]);           \
  GLDS16(Ag + (h) * hh + q1 + (ko), &sA[buf][h][(8 + w) * 512]);
#define STAGE_B(buf, h, ko)                                     \
  GLDS16(Bg + (h) * hh + (ko), &sB[buf][h][w * 512]);           \
  GLDS16(Bg + (h) * hh + q1 + (ko), &sB[buf][h][(8 + w) * 512]);
#define RD_A(buf, m, ks) \
  (*(const bf16x8*)&sA[buf][wm][(((m) * 16 + fr) << 6) + ((((ks) * 4 + g4) ^ sx) << 3)])
#define RD_B(buf, nf, ks) \
  (*(const bf16x8*)&sB[buf][wn >> 1][((((wn & 1) * 64) + (nf) * 16 + fr) << 6) + ((((ks) * 4 + g4) ^ sx) << 3)])

  f32x4 acc[8][4];
#pragma unroll
  for (int m = 0; m < 8; m++)
#pragma unroll
    for (int n = 0; n < 4; n++) acc[m][n] = (f32x4)(0.0f);

  // prologue: stage tile 0 into buf 0
  STAGE_A(0, 0, 0); STAGE_A(0, 1, 0);
  STAGE_B(0, 0, 0); STAGE_B(0, 1, 0);

  for (int t = 0; t < NT; ++t) {
    const int cur = t & 1, nxt = cur ^ 1;
    const size_t ko = (size_t)(t + 1) << 6;
    bf16x8 bfr[4][2], af[2][2];
    // ---- phase 0: stage A halves of t+1, counted vmcnt, B-frags + A m0,m1 ----
    if (t + 1 < NT) {
      STAGE_A(nxt, 0, ko); STAGE_A(nxt, 1, ko);
      asm volatile("s_waitcnt vmcnt(4)" ::: "memory");  // tile t's 8 loads done
    } else {
      asm volatile("s_waitcnt vmcnt(0)" ::: "memory");  // epilogue drain
    }
    blk_barrier();
#pragma unroll
    for (int nf = 0; nf < 4; nf++) {
      bfr[nf][0] = RD_B(cur, nf, 0);
      bfr[nf][1] = RD_B(cur, nf, 1);
    }
    af[0][0] = RD_A(cur, 0, 0); af[0][1] = RD_A(cur, 0, 1);
    af[1][0] = RD_A(cur, 1, 0); af[1][1] = RD_A(cur, 1, 1);
    __builtin_amdgcn_s_setprio(1);
#pragma unroll
    for (int mi = 0; mi < 2; mi++)
#pragma unroll
      for (int nf = 0; nf < 4; nf++) {
        acc[mi][nf] = MFMA16(af[mi][0], bfr[nf][0], acc[mi][nf]);
        acc[mi][nf] = MFMA16(af[mi][1], bfr[nf][1], acc[mi][nf]);
      }
    __builtin_amdgcn_s_setprio(0);
    blk_barrier();
    // ---- phases 1..3: A m{2p,2p+1}; ph1 stages both B halves of t+1 ----
#pragma unroll
    for (int p = 1; p < 4; p++) {
      af[0][0] = RD_A(cur, 2 * p, 0);     af[0][1] = RD_A(cur, 2 * p, 1);
      af[1][0] = RD_A(cur, 2 * p + 1, 0); af[1][1] = RD_A(cur, 2 * p + 1, 1);
      if (p == 1 && t + 1 < NT) {
        STAGE_B(nxt, 0, ko); STAGE_B(nxt, 1, ko);
      }
      blk_barrier();
      __builtin_amdgcn_s_setprio(1);
#pragma unroll
      for (int mi = 0; mi < 2; mi++)
#pragma unroll
        for (int nf = 0; nf < 4; nf++) {
          acc[2 * p + mi][nf] = MFMA16(af[mi][0], bfr[nf][0], acc[2 * p + mi][nf]);
          acc[2 * p + mi][nf] = MFMA16(af[mi][1], bfr[nf][1], acc[2 * p + mi][nf]);
        }
      __builtin_amdgcn_s_setprio(0);
      blk_barrier();
    }
  }

  // epilogue: C row=(l>>4)*4+j, col=fr within each 16x16 frag (m89/m91)
#pragma unroll
  for (int m = 0; m < 8; m++) {
    const int row0 = rowBase + wm * 128 + m * 16 + g4 * 4;
#pragma unroll
    for (int n = 0; n < 4; n++) {
      const int col = colBase + wn * 64 + n * 16 + fr;
      const float bc = bias[col];
      if (mode == 0) {
        const int cmod = col % 384;
        if (cmod >= 256) {
          // V column: transposed-packed store into mixed's dead V-region.
          // (wave-uniform branch: V boundaries are 16-aligned, frag is 16-wide)
          const int h = col / 384, d = cmod - 256;
          const int b = row0 >> 10, t0 = row0 & 1023;
          short4v pv;
#pragma unroll
          for (int j = 0; j < 4; j++) pv[j] = f2bf(acc[m][n][j] + bc);
          *(short4v*)&Cb[(size_t)(b * 1024 + d * 8 + (t0 >> 7)) * Nn +
                         h * 384 + 256 + (t0 & 127)] = pv;
        } else {
#pragma unroll
          for (int j = 0; j < 4; j++)
            Cb[(size_t)(row0 + j) * Nn + col] = f2bf(acc[m][n][j] + bc);
        }
      } else {
#pragma unroll
        for (int j = 0; j < 4; j++) {
          const size_t idx = (size_t)(row0 + j) * Nn + col;
          Cf[idx] = acc[m][n][j] + bc + resid[idx];
        }
      }
    }
  }
#undef STAGE_A
#undef STAGE_B
#undef RD_A
#undef RD_B
}

// ---- bf16 GEMM, 128x256 tile, BK=32, 2 blocks/CU (r6; wins on small grids) ----
__global__ __launch_bounds__(512, 4) void gemm_bt(const short* __restrict__ A,
                                                  const short* __restrict__ B,
                                                  const float* __restrict__ bias,
                                                  const float* __restrict__ resid,
                                                  short* __restrict__ Cb,
                                                  float* __restrict__ Cf,
                                                  int Mtiles, int Nn, int K, int mode) {
  __shared__ short sA[2][128 * 32];  // 8 KiB per buf
  __shared__ short sB[2][256 * 32];  // 16 KiB per buf
  const int tid = threadIdx.x;
  const int w = tid >> 6, l = tid & 63;
  const int wm = w >> 2, wn = w & 3;
  const int fr = l & 15, g4 = l >> 4;
  const int slotx = (g4 ^ ((fr >> 1) & 3)) << 3;

  const int nwg = gridDim.x;
  const int qq = nwg >> 3, rr = nwg & 7;
  const int xcd = blockIdx.x & 7, sub = blockIdx.x >> 3;
  const int swz = (xcd < rr ? xcd * (qq + 1) : rr * (qq + 1) + (xcd - rr) * qq) + sub;
  const int rowBase = (swz % Mtiles) * 128;
  const int colBase = (swz / Mtiles) * 256;

  const int NT = K >> 5;
  const int scol = ((l & 3) ^ ((l >> 3) & 3)) << 3;
  const short* Ag = A + (size_t)(rowBase + w * 16 + (l >> 2)) * K + scol;
  const short* Bg0 = B + (size_t)(colBase + w * 16 + (l >> 2)) * K + scol;
  const short* Bg1 = Bg0 + (size_t)128 * K;

  f32x4 acc[4][4];
#pragma unroll
  for (int m = 0; m < 4; m++)
#pragma unroll
    for (int n = 0; n < 4; n++) acc[m][n] = (f32x4)(0.0f);

  GLDS16(Ag, &sA[0][w * 512]);
  GLDS16(Bg0, &sB[0][w * 512]);
  GLDS16(Bg1, &sB[0][(8 + w) * 512]);

  for (int t = 0; t < NT; ++t) {
    const int cur = t & 1, nxt = cur ^ 1;
    const int ko = (t + 1) << 5;
    if (t + 1 < NT) {
      GLDS16(Ag + ko, &sA[nxt][w * 512]);
      GLDS16(Bg0 + ko, &sB[nxt][w * 512]);
      GLDS16(Bg1 + ko, &sB[nxt][(8 + w) * 512]);
      asm volatile("s_waitcnt vmcnt(3)" ::: "memory");
    } else {
      asm volatile("s_waitcnt vmcnt(0)" ::: "memory");
    }
    blk_barrier();

    bf16x8 af[4], bfr[4];
#pragma unroll
    for (int m = 0; m < 4; m++)
      af[m] = *(const bf16x8*)&sA[cur][(wm * 64 + m * 16 + fr) * 32 + slotx];
#pragma unroll
    for (int nf = 0; nf < 4; nf++)
      bfr[nf] = *(const bf16x8*)&sB[cur][(wn * 64 + nf * 16 + fr) * 32 + slotx];
    __builtin_amdgcn_s_setprio(1);
#pragma unroll
    for (int m = 0; m < 4; m++)
#pragma unroll
      for (int nf = 0; nf < 4; nf++)
        acc[m][nf] = MFMA16(af[m], bfr[nf], acc[m][nf]);
    __builtin_amdgcn_s_setprio(0);
    blk_barrier();
  }

#pragma unroll
  for (int m = 0; m < 4; m++) {
    const int row0 = rowBase + wm * 64 + m * 16 + g4 * 4;
#pragma unroll
    for (int n = 0; n < 4; n++) {
      const int col = colBase + wn * 64 + n * 16 + fr;
      const float bc = bias[col];
#pragma unroll
      for (int j = 0; j < 4; j++) {
        const size_t idx = (size_t)(row0 + j) * Nn + col;
        const float v = acc[m][n][j] + bc;
        if (mode == 0) Cb[idx] = f2bf(v);
        else Cf[idx] = v + resid[idx];
      }
    }
  }
}

// ------------- flash attention v2: LDS-staged K/V, swapped QK^T ----------------
// V read from mixed's dead V-region in VT layout (written by gemm_bt8 mode 0):
// VT(b,h,d,t) @ mixed row (b*1024 + d*8 + (t>>7)), col (h*384+256+(t&127)).
// Tile t-range [kt,kt+64) never crosses a 128-block, so (t>>7) uniform per tile.
__global__ __launch_bounds__(256, 2) void attn_kernel(const short* __restrict__ mixed,
                                                      short* __restrict__ ctx) {
  __shared__ short sK[2][64 * 128];
  __shared__ short sV[2][128 * 64];
  __shared__ unsigned p_lds[4][16 * 36];
  const int tid = threadIdx.x;
  const int w = tid >> 6, l = tid & 63;
  const int g = l >> 4, f = l & 15, f7 = l & 7;

  const int bidx = blockIdx.x;
  const int xcd = bidx & 7, idx = bidx >> 3;
  const int bh = (xcd << 4) | (idx >> 4);
  const int qt = idx & 15;
  const int b = bh >> 5, h = bh & 31;
  const int qw = qt * 64 + w * 16;
  const float scale = 0.08838834764831845f;
  const float slope = exp2f(-0.25f * (float)(h + 1));

  const short* qptr = mixed + (size_t)b * 1024 * 12288 + h * 384;
  const short* kptr = qptr + 128;
  const short* vbase = qptr + 256;  // VT region base for (b,h)

  bf16x8 qf[4];
  {
    const short* qrow = qptr + (size_t)(qw + f) * 12288 + (g << 3);
#pragma unroll
    for (int ks = 0; ks < 4; ks++) qf[ks] = *(const bf16x8*)(qrow + ks * 32);
  }

#define STAGE_K(buf, kt)                                                        \
  {                                                                             \
    _Pragma("unroll") for (int c4 = 0; c4 < 4; c4++) {                          \
      const int c = c4 * 4 + w;                                                 \
      const int r = c * 4 + (l >> 4);                                           \
      GLDS16(kptr + (size_t)((kt) + r) * 12288 + (((l & 15) ^ (r & 7)) << 3),   \
             &sK[buf][c << 9]);                                                 \
    }                                                                           \
  }
  // V stage from VT layout: d-row r, t = kt + ((l&7)^(r&7))*8 .. +7 contiguous
#define STAGE_V(buf, kt)                                                        \
  {                                                                             \
    _Pragma("unroll") for (int c4 = 0; c4 < 4; c4++) {                          \
      const int c = c4 * 4 + w;                                                 \
      const int r = c * 8 + (l >> 3);                                           \
      const int ts = ((l & 7) ^ (r & 7)) << 3;                                  \
      GLDS16(vbase + (size_t)(r * 8 + ((kt) >> 7)) * 12288 + (((kt) & 127) + ts), \
             &sV[buf][c << 9]);                                                 \
    }                                                                           \
  }

  f32x4 acc[8];
#pragma unroll
  for (int n = 0; n < 8; n++) acc[n] = (f32x4)(0.0f);
  float mrun = -1e30f, lrun = 0.0f;
  const int q = qw + f;
  unsigned* pw = p_lds[w];

  const int TT = qt + 1;
  STAGE_K(0, 0);
  STAGE_V(0, 0);

  for (int t = 0; t < TT; ++t) {
    const int cur = t & 1, nxt = cur ^ 1;
    const int kt = t << 6;
    if (t + 1 < TT) {
      STAGE_K(nxt, kt + 64);
      STAGE_V(nxt, kt + 64);
      asm volatile("s_waitcnt vmcnt(8)" ::: "memory");
    } else {
      asm volatile("s_waitcnt vmcnt(0)" ::: "memory");
    }
    blk_barrier();

    f32x4 s[4];
#pragma unroll
    for (int ksub = 0; ksub < 4; ksub++) {
      s[ksub] = (f32x4)(0.0f);
      const int r = ksub * 16 + f;
#pragma unroll
      for (int ks = 0; ks < 4; ks++) {
        bf16x8 kf = *(const bf16x8*)&sK[cur][(r << 7) + ((((ks << 2) + g) ^ f7) << 3)];
        s[ksub] = MFMA16(kf, qf[ks], s[ksub]);
      }
    }

    float ev[4][4];
    float tmax = -1e30f;
#pragma unroll
    for (int ksub = 0; ksub < 4; ksub++)
#pragma unroll
      for (int j = 0; j < 4; j++) {
        const int k = kt + ksub * 16 + g * 4 + j;
        float v = s[ksub][j] * scale + slope * (float)k;
        if (k > q) v = -1e30f;
        ev[ksub][j] = v;
        tmax = fmaxf(tmax, v);
      }
    tmax = fmaxf(tmax, __shfl_xor(tmax, 16));
    tmax = fmaxf(tmax, __shfl_xor(tmax, 32));
    const float mnew = fmaxf(mrun, tmax);
    const float asc = __expf(mrun - mnew);
    float psum = 0.0f;
    unsigned* pr = pw + f * 36;
#pragma unroll
    for (int ksub = 0; ksub < 4; ksub++) {
      float e0 = __expf(ev[ksub][0] - mnew);
      float e1 = __expf(ev[ksub][1] - mnew);
      float e2 = __expf(ev[ksub][2] - mnew);
      float e3 = __expf(ev[ksub][3] - mnew);
      psum += (e0 + e1) + (e2 + e3);
      unsigned w0 = (unsigned)(unsigned short)f2bf(e0) |
                    ((unsigned)(unsigned short)f2bf(e1) << 16);
      unsigned w1 = (unsigned)(unsigned short)f2bf(e2) |
                    ((unsigned)(unsigned short)f2bf(e3) << 16);
      pr[ksub * 8 + g * 2] = w0;
      pr[ksub * 8 + g * 2 + 1] = w1;
    }
    psum += __shfl_xor(psum, 16);
    psum += __shfl_xor(psum, 32);
    lrun = lrun * asc + psum;
    mrun = mnew;

    float ascB[4];
#pragma unroll
    for (int j = 0; j < 4; j++) ascB[j] = __shfl(asc, 20 * g + j);
#pragma unroll
    for (int n = 0; n < 8; n++)
#pragma unroll
      for (int j = 0; j < 4; j++) acc[n][j] *= ascB[j];

    bf16x8 pa0 = *(const bf16x8*)(pw + f * 36 + (g << 2));
    bf16x8 pa1 = *(const bf16x8*)(pw + f * 36 + 16 + (g << 2));
#pragma unroll
    for (int n = 0; n < 8; n++) {
      const int dr = (n << 4) + f;
      bf16x8 vf0 = *(const bf16x8*)&sV[cur][(dr << 6) + ((g ^ f7) << 3)];
      acc[n] = MFMA16(pa0, vf0, acc[n]);
      bf16x8 vf1 = *(const bf16x8*)&sV[cur][(dr << 6) + (((4 + g) ^ f7) << 3)];
      acc[n] = MFMA16(pa1, vf1, acc[n]);
    }
    blk_barrier();
  }

  const float linv = 1.0f / lrun;
  float invB[4];
#pragma unroll
  for (int j = 0; j < 4; j++) invB[j] = __shfl(linv, 20 * g + j);
  const int trow = b * 1024 + qw + (g << 2);
#pragma unroll
  for (int n = 0; n < 8; n++) {
    const int col = h * 128 + (n << 4) + f;
#pragma unroll
    for (int j = 0; j < 4; j++)
      ctx[(size_t)(trow + j) * 4096 + col] = f2bf(acc[n][j] * invB[j]);
  }
#undef STAGE_K
#undef STAGE_V
}

extern "C" void kernel_launch(void* const* d_in, const int* in_sizes, int n_in,
                              void* d_out, int out_size, void* d_ws, size_t ws_size,
                              hipStream_t stream) {
  const float* hs = (const float*)d_in[0];
  const float* resid = (const float*)d_in[1];
  const float* qkv_w = (const float*)d_in[2];
  const float* qkv_b = (const float*)d_in[3];
  const float* dense_w = (const float*)d_in[4];
  const float* dense_b = (const float*)d_in[5];
  float* out = (float*)d_out;

  short* hs_b = (short*)d_ws;
  short* wqkv_b = hs_b + (size_t)16777216;
  short* wd_b = wqkv_b + (size_t)50331648;
  short* mixed = wd_b + (size_t)16777216;
  short* ctx = hs_b;    // alias: hs_b dead after gemm1

  // all three fp32->bf16 converts in one launch
  cvt3_kernel<<<2048, 256, 0, stream>>>(hs, hs_b, 16777216 / 4,
                                        qkv_w, wqkv_b, 50331648 / 4,
                                        dense_w, wd_b, 16777216 / 4);
  // qkv: 256^2 structure; V-columns stored transposed in mixed (vtrans fused)
  gemm_bt8<<<dim3(48 * 16), 512, 0, stream>>>(hs_b, wqkv_b, qkv_b, nullptr,
                                              mixed, nullptr, 16, 12288, 4096, 0);
  attn_kernel<<<2048, 256, 0, stream>>>(mixed, ctx);
  // dense: small grid -> 128x256 2-blocks/CU TLP structure (r6)
  gemm_bt<<<dim3(32 * 16), 512, 0, stream>>>(ctx, wd_b, dense_b, resid,
                                             nullptr, out, 32, 4096, 4096, 1);
}